// Round 16
// baseline (454.154 us; speedup 1.0000x reference)
//
#include <hip/hip_runtime.h>
#include <math.h>

constexpr int CIN      = 256;
constexpr int HW       = 16384;       // 128*128
constexpr int NMID     = 64;
constexpr int HWTILE   = 128;         // spatial positions per block (4 waves x 32)
constexpr int TILE_B   = 8192;        // padded A-tile image (80 rows x 80B)
constexpr int NORM_OFF = 512;         // mask (8*64) floats first
constexpr int K_OFF    = 75497984;    // 512 + 8*64*9*16384
constexpr int IDX_OFF  = 75497985;
constexpr int XBAR_OFF = 64 * 2 * TILE_B;  // xsum[8][256] after 1 MB W image

typedef __attribute__((ext_vector_type(8))) short bf16x8;   // 8 bf16 = 4 VGPR
typedef __attribute__((ext_vector_type(4))) float f32x4;

__device__ __forceinline__ unsigned bf16_rne(float f) {
    unsigned u = __float_as_uint(f);
    return (u + 0x7fffu + ((u >> 16) & 1u)) >> 16;          // bf16 bits, RNE
}

__device__ __forceinline__ void gload_lds16(const void* gsrc, void* ldst) {
    __builtin_amdgcn_global_load_lds(
        (const __attribute__((address_space(1))) void*)gsrc,
        (__attribute__((address_space(3))) void*)ldst, 16, 0, 0);
}

// ---------------------------------------------------------------------------
// Repack W into MFMA A-fragment image, split bf16 hi/lo (r11's exact 2-part
// layout — the only configuration whose fused_main codegen holds the B-array
// in registers). Row permutation: p = (idx/4)*16 + q*4 + idx%4,
// q=(mid&7)>>1, idx=(mid&1)*10+j. Tile (g*8+kc, part): 80 rows x 32 c.
__global__ __launch_bounds__(256) void prep_w(const float* __restrict__ Wm,
                                              char* __restrict__ ws)
{
    const int o = blockIdx.x;         // original W row 0..639
    const int c = threadIdx.x;        // 0..255
    int mid, j;
    if (o < NMID) { mid = o; j = 0; }
    else          { mid = (o - NMID) / 9; j = 1 + (o - NMID) % 9; }
    const int g  = mid >> 3, ml = mid & 7, q = ml >> 1, mi = ml & 1;
    const int idx = mi * 10 + j;
    const int p   = (idx >> 2) * 16 + q * 4 + (idx & 3);    // tile row 0..79
    const float w = Wm[(size_t)o * CIN + c];
    const unsigned hi = bf16_rne(w);
    const float    fl = w - __uint_as_float(hi << 16);
    const unsigned lo = bf16_rne(fl);
    const int kc = c >> 5, cc = c & 31;
    char* base = ws + (size_t)((g * 8 + kc) * 2) * TILE_B + p * 80 + cc * 2;
    *(unsigned short*)(base)          = (unsigned short)hi;
    *(unsigned short*)(base + TILE_B) = (unsigned short)lo;
}

// ---------------------------------------------------------------------------
// Zero the fp32 x-channel-sum accumulator (8 batches x 256 channels) in d_ws.
__global__ __launch_bounds__(512) void zero_xbar_kernel(float* __restrict__ xbar) {
    #pragma unroll
    for (int i = 0; i < 4; ++i) xbar[i * 512 + threadIdx.x] = 0.0f;
}

// ---------------------------------------------------------------------------
// Split-bf16 MFMA GEMM (640x256 @ 256x128-tile) + lane-local softmax epilogue.
// r11's exact structure (2-part image, 4-op STAGE, Bhi+Blo register arrays,
// 3-buffer depth-2 LDS pipeline, g-rotation, de-chained MFMA passes, nt
// stores) with two changes:
//  (1) MFMA pass 3 (Al x Bh) dropped — kept passes = Wh*(xh+xl) = Wh*x; the
//      W-lo term only affects norm_kernels by ~8e-3 (threshold 0.031). Al's
//      ds_reads DCE out; Bhi AND Blo stay live (same regalloc as r11).
//  (2) score path made EXACT: pass A accumulates fp32 channel sums of x into
//      xbar (volatile loads — no CSE into pass B), finalize does the fp32
//      dot. Epilogue score atomic removed (epi VMEM 38 -> 36).
__global__ __launch_bounds__(256, 2) void fused_main(const float* __restrict__ x,
                                                     const char* __restrict__ wimg,
                                                     const float* __restrict__ bvec,
                                                     float* __restrict__ out,
                                                     float* __restrict__ xbar)
{
    __shared__ __align__(16) char atile[3][2][TILE_B];   // 48 KB [buf][hi/lo]
    __shared__ float bsh[640];

    const int tid  = threadIdx.x;
    const int wave = tid >> 6, lane = tid & 63;
    const int q    = lane >> 4, m = lane & 15;
    const int b    = blockIdx.x >> 7;
    const int hw0  = (blockIdx.x & 127) * HWTILE;
    const int grot = (blockIdx.x >> 3) & 7;      // g-phase rotation

#define STAGE(tile, buf) do {                                                  \
    const char* _s = wimg + (size_t)(tile) * 2 * TILE_B;                       \
    char* _d = &atile[buf][0][0];                                              \
    gload_lds16(_s + tid * 16,                 _d + tid * 16);                 \
    gload_lds16(_s + 4096 + tid * 16,          _d + 4096 + tid * 16);          \
    gload_lds16(_s + TILE_B + tid * 16,        _d + TILE_B + tid * 16);        \
    gload_lds16(_s + TILE_B + 4096 + tid * 16, _d + TILE_B + 4096 + tid * 16); \
} while (0)

    // tiles consumed in rotated order; stage the first two now
    const int t0 = grot * 8;
    STAGE(t0, 0);
    STAGE(t0 + 1, 1);

    const float* xb = x + (size_t)b * CIN * HW + hw0 + wave * 32 + m;

    // ---- pass A: exact fp32 channel sums (volatile: no CSE with pass B) ----
    {
        const volatile float* xv = xb;
        #pragma unroll 1
        for (int kc = 0; kc < 8; ++kc) {
            float xacc[8];
            #pragma unroll
            for (int i = 0; i < 8; ++i) xacc[i] = 0.0f;
            #pragma unroll
            for (int t = 0; t < 2; ++t)
                #pragma unroll
                for (int i = 0; i < 8; ++i)
                    xacc[i] += xv[t * 16 + (size_t)(kc * 32 + q * 8 + i) * HW];
            #pragma unroll
            for (int i = 0; i < 8; ++i) {
                xacc[i] += __shfl_xor(xacc[i], 1);
                xacc[i] += __shfl_xor(xacc[i], 2);
                xacc[i] += __shfl_xor(xacc[i], 4);
                xacc[i] += __shfl_xor(xacc[i], 8);
            }
            if (m == 0) {
                #pragma unroll
                for (int i = 0; i < 8; ++i)
                    atomicAdd(&xbar[b * CIN + kc * 32 + q * 8 + i], xacc[i]);
            }
        }
    }

    // ---- pass B: B fragments, r11's exact loop nest; split hi/lo ----
    bf16x8 Bhi[2][8], Blo[2][8];
    #pragma unroll
    for (int t = 0; t < 2; ++t)
        #pragma unroll
        for (int kc = 0; kc < 8; ++kc) {
            float f[8];
            #pragma unroll
            for (int i = 0; i < 8; ++i)
                f[i] = xb[t * 16 + (size_t)(kc * 32 + q * 8 + i) * HW];
            union { unsigned u[4]; bf16x8 v; } uh, ul;
            #pragma unroll
            for (int jj = 0; jj < 4; ++jj) {
                const unsigned h0 = bf16_rne(f[2*jj]), h1 = bf16_rne(f[2*jj+1]);
                const float r0 = f[2*jj]   - __uint_as_float(h0 << 16);
                const float r1 = f[2*jj+1] - __uint_as_float(h1 << 16);
                uh.u[jj] = h0 | (h1 << 16);
                ul.u[jj] = bf16_rne(r0) | (bf16_rne(r1) << 16);
            }
            Bhi[t][kc] = uh.v; Blo[t][kc] = ul.v;
        }
    for (int i = tid; i < 640; i += 256) bsh[i] = bvec[i];
    asm volatile("s_waitcnt lgkmcnt(0)" ::: "memory");
    __builtin_amdgcn_s_barrier();

    int cur = 0;                         // LDS buffer holding current tile
    #pragma unroll 1
    for (int gg = 0; gg < 8; ++gg) {
        const int g = (gg + grot) & 7;   // rotated output-group index
        f32x4 acc[5][2];
        #pragma unroll
        for (int ot = 0; ot < 5; ++ot)
            #pragma unroll
            for (int t = 0; t < 2; ++t) acc[ot][t] = (f32x4){0.f, 0.f, 0.f, 0.f};

        #pragma unroll
        for (int kc = 0; kc < 8; ++kc) {
            const int seq = gg * 8 + kc;             // consumption order 0..63
            const int nb  = (cur >= 1) ? cur - 1 : 2; // (cur+2)%3
            if (seq <= 61) {
                const int nseq = seq + 2;            // tile 2 ahead, rotated
                STAGE((((nseq >> 3) + grot) & 7) * 8 + (nseq & 7), nb);
            }
            // FIFO-counted waits (4 VMEM/stage, 36 nt-stores/epilogue):
            //  steady: stages seq+1, seq+2 in flight -> vmcnt(8)
            //  kc<2 after an epilogue: 4 + 36 + 4 after stage(seq) -> vmcnt(44)
            //  tail: seq=62 -> vmcnt(4); seq=63 -> vmcnt(0)
            if (gg == 7 && kc == 7)      asm volatile("s_waitcnt vmcnt(0)"  ::: "memory");
            else if (gg == 7 && kc == 6) asm volatile("s_waitcnt vmcnt(4)"  ::: "memory");
            else if (gg > 0 && kc < 2)   asm volatile("s_waitcnt vmcnt(44)" ::: "memory");
            else                         asm volatile("s_waitcnt vmcnt(8)"  ::: "memory");
            __builtin_amdgcn_s_barrier();

            const char* ahi = &atile[cur][0][m * 80 + q * 16];
            bf16x8 Ah[5];
            #pragma unroll
            for (int ot = 0; ot < 5; ++ot)
                Ah[ot] = *(const bf16x8*)(ahi + ot * 1280);
            __builtin_amdgcn_s_setprio(1);
            // pass 1: Ah*Bh — 10 independent MFMAs
            #pragma unroll
            for (int ot = 0; ot < 5; ++ot)
                #pragma unroll
                for (int t2 = 0; t2 < 2; ++t2)
                    acc[ot][t2] = __builtin_amdgcn_mfma_f32_16x16x32_bf16(Ah[ot], Bhi[t2][kc], acc[ot][t2], 0, 0, 0);
            // pass 2: Ah*Bl  (W-lo pass dropped; norm error ~8e-3 < 0.031)
            #pragma unroll
            for (int ot = 0; ot < 5; ++ot)
                #pragma unroll
                for (int t2 = 0; t2 < 2; ++t2)
                    acc[ot][t2] = __builtin_amdgcn_mfma_f32_16x16x32_bf16(Ah[ot], Blo[t2][kc], acc[ot][t2], 0, 0, 0);
            __builtin_amdgcn_s_setprio(0);

            // ---- epilogue at kc==7 (before the phase-end barrier):
            //      lane owns mids q*2+mi at hw = hw0 + wave*32 + t2*16 + m ----
            if (kc == 7) {
                #pragma unroll
                for (int mi = 0; mi < 2; ++mi) {
                    const int gmid = g * 8 + q * 2 + mi;
                    const int i0 = mi * 10;
                    float bj[9];
                    #pragma unroll
                    for (int jj = 0; jj < 9; ++jj) bj[jj] = bsh[NMID + gmid * 9 + jj];
                    #pragma unroll
                    for (int t2 = 0; t2 < 2; ++t2) {
                        float p[9];
                        #pragma unroll
                        for (int jj = 0; jj < 9; ++jj) {
                            const int idx = i0 + 1 + jj;
                            p[jj] = acc[idx >> 2][t2][idx & 3] + bj[jj];
                        }
                        float mx = p[0];
                        #pragma unroll
                        for (int jj = 1; jj < 9; ++jj) mx = fmaxf(mx, p[jj]);
                        float ss = 0.f;
                        #pragma unroll
                        for (int jj = 0; jj < 9; ++jj) { p[jj] = __expf(p[jj] - mx); ss += p[jj]; }
                        const float rs = 1.0f / ss;
                        float* ob = out + NORM_OFF
                                  + ((size_t)((b * NMID + gmid) * 9)) * HW
                                  + hw0 + wave * 32 + t2 * 16 + m;
                        #pragma unroll
                        for (int jj = 0; jj < 9; ++jj)
                            __builtin_nontemporal_store(p[jj] * rs, ob + (size_t)jj * HW);
                    }
                }
            }
            asm volatile("s_waitcnt lgkmcnt(0)" ::: "memory");
            __builtin_amdgcn_s_barrier();
            cur = (cur == 2) ? 0 : cur + 1;
        }
    }
#undef STAGE
}

// ---------------------------------------------------------------------------
// One block, 8 waves; wave b handles batch b, lane = mid. EXACT fp32 score:
// sigmoid(dot(W_score[mid], xsum[b])/HW + bias). Then stable top-k (desc
// value, tie -> lower index), mask, k, indices.
__global__ __launch_bounds__(512) void finalize_kernel(float* __restrict__ out,
                                                       const float* __restrict__ Wm,
                                                       const float* __restrict__ bvec,
                                                       const float* __restrict__ xbar,
                                                       int k)
{
    const int tid  = threadIdx.x;
    const int b    = tid >> 6;
    const int lane = tid & 63;                  // mid
    const float4* wr = (const float4*)(Wm + (size_t)lane * CIN);
    const float4* xr = (const float4*)(xbar + b * CIN);
    float dot = 0.f;
    #pragma unroll 8
    for (int c4 = 0; c4 < CIN / 4; ++c4) {
        const float4 w = wr[c4], xv = xr[c4];
        dot += w.x * xv.x + w.y * xv.y + w.z * xv.z + w.w * xv.w;
    }
    const float sv = 1.0f / (1.0f + __expf(-(dot * (1.0f / 16384.0f) + bvec[lane])));
    float val      = sv;
    float selected = 0.0f;
    for (int t = 0; t < k; ++t) {
        float bvv = val;
        int   bi  = lane;
        #pragma unroll
        for (int off = 32; off >= 1; off >>= 1) {
            const float ov = __shfl_xor(bvv, off);
            const int   oi = __shfl_xor(bi, off);
            if (ov > bvv || (ov == bvv && oi < bi)) { bvv = ov; bi = oi; }
        }
        if (lane == bi) { val = -INFINITY; selected = 1.0f; }
        if (lane == 0) out[IDX_OFF + b * k + t] = (float)bi;
    }
    out[b * NMID + lane] = selected;            // mask
    if (tid == 0) out[K_OFF] = (float)k;
}

// ---------------------------------------------------------------------------
extern "C" void kernel_launch(void* const* d_in, const int* in_sizes, int n_in,
                              void* d_out, int out_size, void* d_ws, size_t ws_size,
                              hipStream_t stream)
{
    const float* x    = (const float*)d_in[0];
    const float* Wm   = (const float*)d_in[1];
    const float* bvec = (const float*)d_in[2];
    float* out  = (float*)d_out;
    char*  ws   = (char*)d_ws;              // 1 MB W image + 8 KB xbar
    float* xbar = (float*)(ws + XBAR_OFF);

    // out_size = 512 (mask) + 75497472 (norm_kernels) + 1 (k) + 8*k (indices)
    const int k = (out_size - IDX_OFF) / 8;

    prep_w<<<640, 256, 0, stream>>>(Wm, ws);
    zero_xbar_kernel<<<1, 512, 0, stream>>>(xbar);
    fused_main<<<8 * (HW / HWTILE), 256, 0, stream>>>(x, ws, bvec, out, xbar);
    finalize_kernel<<<1, 512, 0, stream>>>(out, Wm, bvec, xbar, k);
}

// Round 17
// 184.837 us; speedup vs baseline: 2.4571x; 2.4571x over previous
//
#include <hip/hip_runtime.h>
#include <math.h>

constexpr int CIN      = 256;
constexpr int HW       = 16384;       // 128*128
constexpr int NMID     = 64;
constexpr int HWTILE   = 128;         // spatial positions per block (4 waves x 32)
constexpr int TILE_B   = 8192;        // padded A-tile part (80 rows x 80B)
constexpr int NORM_OFF = 512;         // mask (8*64) floats first
constexpr int K_OFF    = 75497984;    // 512 + 8*64*9*16384
constexpr int IDX_OFF  = 75497985;
constexpr int XPART_OFF = 64 * 2 * TILE_B;   // per-block partials after 1 MB W image

typedef __attribute__((ext_vector_type(8))) short bf16x8;   // 8 bf16 = 4 VGPR
typedef __attribute__((ext_vector_type(4))) float f32x4;

__device__ __forceinline__ unsigned bf16_rne(float f) {
    unsigned u = __float_as_uint(f);
    return (u + 0x7fffu + ((u >> 16) & 1u)) >> 16;          // bf16 bits, RNE
}

__device__ __forceinline__ void gload_lds16(const void* gsrc, void* ldst) {
    __builtin_amdgcn_global_load_lds(
        (const __attribute__((address_space(1))) void*)gsrc,
        (__attribute__((address_space(3))) void*)ldst, 16, 0, 0);
}

// ---------------------------------------------------------------------------
// Repack W into MFMA A-fragment image, split bf16 hi/lo (byte-identical to the
// proven r11 prep). Row permutation lands each mid's 10 outputs in ONE lane's
// D-fragments: p = (idx/4)*16 + q*4 + idx%4, q=(mid&7)>>1, idx=(mid&1)*10+j.
// fused_main now stages only the hi part; lo tiles are simply unused.
__global__ __launch_bounds__(256) void prep_w(const float* __restrict__ Wm,
                                              char* __restrict__ ws)
{
    const int o = blockIdx.x;         // original W row 0..639
    const int c = threadIdx.x;        // 0..255
    int mid, j;
    if (o < NMID) { mid = o; j = 0; }
    else          { mid = (o - NMID) / 9; j = 1 + (o - NMID) % 9; }
    const int g  = mid >> 3, ml = mid & 7, q = ml >> 1, mi = ml & 1;
    const int idx = mi * 10 + j;
    const int p   = (idx >> 2) * 16 + q * 4 + (idx & 3);    // tile row 0..79
    const float w = Wm[(size_t)o * CIN + c];
    const unsigned hi = bf16_rne(w);
    const float    fl = w - __uint_as_float(hi << 16);
    const unsigned lo = bf16_rne(fl);
    const int kc = c >> 5, cc = c & 31;
    char* base = ws + (size_t)((g * 8 + kc) * 2) * TILE_B + p * 80 + cc * 2;
    *(unsigned short*)(base)          = (unsigned short)hi;
    *(unsigned short*)(base + TILE_B) = (unsigned short)lo;
}

// ---------------------------------------------------------------------------
// Split-bf16 MFMA GEMM (640x256 @ 256x128-tile) + lane-local softmax epilogue.
// r11's proven core. Changes vs r16 (which isolated pass A as the 2.4x cost):
//  (1) pass A rewritten: NO volatile, NO atomics — thread tid = channel, 32
//      independent float4 loads (lane-local sum over this block's 128 hw),
//      one plain store to xpart[bid][c]. finalize reduces the 128 partials.
//  (2) A-lo tiles never staged (pass 3 dropped): 2-op STAGE, 24 KB LDS.
//      Kept MFMA passes = Wh*(xh+xl) = Wh*x; norm error ~8e-3 << 0.031.
__global__ __launch_bounds__(256, 2) void fused_main(const float* __restrict__ x,
                                                     const char* __restrict__ wimg,
                                                     const float* __restrict__ bvec,
                                                     float* __restrict__ out,
                                                     float* __restrict__ xpart)
{
    __shared__ __align__(16) char atile[3][TILE_B];      // 24 KB (hi part only)
    __shared__ float bsh[640];

    const int tid  = threadIdx.x;
    const int wave = tid >> 6, lane = tid & 63;
    const int q    = lane >> 4, m = lane & 15;
    const int b    = blockIdx.x >> 7;
    const int hw0  = (blockIdx.x & 127) * HWTILE;
    const int grot = (blockIdx.x >> 3) & 7;      // g-phase rotation

#define STAGE(tile, buf) do {                                                  \
    const char* _s = wimg + (size_t)(tile) * 2 * TILE_B;   /* hi part */       \
    char* _d = &atile[buf][0];                                                 \
    gload_lds16(_s + tid * 16,        _d + tid * 16);                          \
    gload_lds16(_s + 4096 + tid * 16, _d + 4096 + tid * 16);                   \
} while (0)

    // tiles consumed in rotated order; stage the first two now (4 VMEM ops)
    const int t0 = grot * 8;
    STAGE(t0, 0);
    STAGE(t0 + 1, 1);

    // ---- pass A: exact fp32 per-channel partial sums (channel-per-lane,
    //      32 independent float4 loads, lane-local; 1 plain store) ----
    {
        const float* xc = x + (size_t)b * CIN * HW + (size_t)tid * HW + hw0;
        float4 s4 = make_float4(0.f, 0.f, 0.f, 0.f);
        #pragma unroll
        for (int u = 0; u < 32; ++u) {
            const float4 v = *(const float4*)(xc + u * 4);
            s4.x += v.x; s4.y += v.y; s4.z += v.z; s4.w += v.w;
        }
        xpart[(size_t)blockIdx.x * CIN + tid] = (s4.x + s4.y) + (s4.z + s4.w);
    }

    // ---- pass B: B fragments, r11's exact loop nest; split hi/lo ----
    bf16x8 Bhi[2][8], Blo[2][8];
    const float* xb = x + (size_t)b * CIN * HW + hw0 + wave * 32 + m;
    #pragma unroll
    for (int t = 0; t < 2; ++t)
        #pragma unroll
        for (int kc = 0; kc < 8; ++kc) {
            float f[8];
            #pragma unroll
            for (int i = 0; i < 8; ++i)
                f[i] = xb[t * 16 + (size_t)(kc * 32 + q * 8 + i) * HW];
            union { unsigned u[4]; bf16x8 v; } uh, ul;
            #pragma unroll
            for (int jj = 0; jj < 4; ++jj) {
                const unsigned h0 = bf16_rne(f[2*jj]), h1 = bf16_rne(f[2*jj+1]);
                const float r0 = f[2*jj]   - __uint_as_float(h0 << 16);
                const float r1 = f[2*jj+1] - __uint_as_float(h1 << 16);
                uh.u[jj] = h0 | (h1 << 16);
                ul.u[jj] = bf16_rne(r0) | (bf16_rne(r1) << 16);
            }
            Bhi[t][kc] = uh.v; Blo[t][kc] = ul.v;
        }
    for (int i = tid; i < 640; i += 256) bsh[i] = bvec[i];
    asm volatile("s_waitcnt lgkmcnt(0)" ::: "memory");
    __builtin_amdgcn_s_barrier();

    int cur = 0;                         // LDS buffer holding current tile
    #pragma unroll 1
    for (int gg = 0; gg < 8; ++gg) {
        const int g = (gg + grot) & 7;   // rotated output-group index
        f32x4 acc[5][2];
        #pragma unroll
        for (int ot = 0; ot < 5; ++ot)
            #pragma unroll
            for (int t = 0; t < 2; ++t) acc[ot][t] = (f32x4){0.f, 0.f, 0.f, 0.f};

        #pragma unroll
        for (int kc = 0; kc < 8; ++kc) {
            const int seq = gg * 8 + kc;             // consumption order 0..63
            const int nb  = (cur >= 1) ? cur - 1 : 2; // (cur+2)%3
            if (seq <= 61) {
                const int nseq = seq + 2;            // tile 2 ahead, rotated
                STAGE((((nseq >> 3) + grot) & 7) * 8 + (nseq & 7), nb);
            }
            // FIFO-counted waits (2 VMEM/stage, 36 nt-stores/epilogue):
            //  steady: stages seq+1, seq+2 in flight -> vmcnt(4)
            //  kc<2 after an epilogue: 2 + 36 + 2 younger than stage(seq)
            //    (kc==1: 36 + 2 + 2 younger than stage(seq+1)) -> vmcnt(40)
            //  tail: seq=62 -> vmcnt(2); seq=63 -> vmcnt(0)
            if (gg == 7 && kc == 7)      asm volatile("s_waitcnt vmcnt(0)"  ::: "memory");
            else if (gg == 7 && kc == 6) asm volatile("s_waitcnt vmcnt(2)"  ::: "memory");
            else if (gg > 0 && kc < 2)   asm volatile("s_waitcnt vmcnt(40)" ::: "memory");
            else                         asm volatile("s_waitcnt vmcnt(4)"  ::: "memory");
            __builtin_amdgcn_s_barrier();

            const char* ahi = &atile[cur][m * 80 + q * 16];
            bf16x8 Ah[5];
            #pragma unroll
            for (int ot = 0; ot < 5; ++ot)
                Ah[ot] = *(const bf16x8*)(ahi + ot * 1280);
            __builtin_amdgcn_s_setprio(1);
            // pass 1: Ah*Bh — 10 independent MFMAs
            #pragma unroll
            for (int ot = 0; ot < 5; ++ot)
                #pragma unroll
                for (int t2 = 0; t2 < 2; ++t2)
                    acc[ot][t2] = __builtin_amdgcn_mfma_f32_16x16x32_bf16(Ah[ot], Bhi[t2][kc], acc[ot][t2], 0, 0, 0);
            // pass 2: Ah*Bl
            #pragma unroll
            for (int ot = 0; ot < 5; ++ot)
                #pragma unroll
                for (int t2 = 0; t2 < 2; ++t2)
                    acc[ot][t2] = __builtin_amdgcn_mfma_f32_16x16x32_bf16(Ah[ot], Blo[t2][kc], acc[ot][t2], 0, 0, 0);
            __builtin_amdgcn_s_setprio(0);

            // ---- epilogue at kc==7 (before the phase-end barrier):
            //      lane owns mids q*2+mi at hw = hw0 + wave*32 + t2*16 + m ----
            if (kc == 7) {
                #pragma unroll
                for (int mi = 0; mi < 2; ++mi) {
                    const int gmid = g * 8 + q * 2 + mi;
                    const int i0 = mi * 10;
                    float bj[9];
                    #pragma unroll
                    for (int jj = 0; jj < 9; ++jj) bj[jj] = bsh[NMID + gmid * 9 + jj];
                    #pragma unroll
                    for (int t2 = 0; t2 < 2; ++t2) {
                        float p[9];
                        #pragma unroll
                        for (int jj = 0; jj < 9; ++jj) {
                            const int idx = i0 + 1 + jj;
                            p[jj] = acc[idx >> 2][t2][idx & 3] + bj[jj];
                        }
                        float mx = p[0];
                        #pragma unroll
                        for (int jj = 1; jj < 9; ++jj) mx = fmaxf(mx, p[jj]);
                        float ss = 0.f;
                        #pragma unroll
                        for (int jj = 0; jj < 9; ++jj) { p[jj] = __expf(p[jj] - mx); ss += p[jj]; }
                        const float rs = 1.0f / ss;
                        float* ob = out + NORM_OFF
                                  + ((size_t)((b * NMID + gmid) * 9)) * HW
                                  + hw0 + wave * 32 + t2 * 16 + m;
                        #pragma unroll
                        for (int jj = 0; jj < 9; ++jj)
                            __builtin_nontemporal_store(p[jj] * rs, ob + (size_t)jj * HW);
                    }
                }
            }
            asm volatile("s_waitcnt lgkmcnt(0)" ::: "memory");
            __builtin_amdgcn_s_barrier();
            cur = (cur == 2) ? 0 : cur + 1;
        }
    }
#undef STAGE
}

// ---------------------------------------------------------------------------
// One block, 8 waves. First reduce the 128 per-block partials -> exact fp32
// xsum[8][256] in LDS. Then wave b, lane mid: exact fp32 score
// sigmoid(dot(W_score[mid], xsum[b])/HW + bias); stable top-k (desc value,
// tie -> lower index), mask, k, indices.
__global__ __launch_bounds__(512) void finalize_kernel(float* __restrict__ out,
                                                       const float* __restrict__ Wm,
                                                       const float* __restrict__ bvec,
                                                       const float* __restrict__ xpart,
                                                       int k)
{
    __shared__ float xs[8 * CIN];               // 8 KB
    const int tid = threadIdx.x;
    #pragma unroll
    for (int r = 0; r < 4; ++r) {
        const int idx = tid + 512 * r;          // 0..2047 -> (b, c)
        const int bb = idx >> 8, cc = idx & 255;
        float s = 0.f;
        #pragma unroll 8
        for (int h = 0; h < 128; ++h)
            s += xpart[((size_t)(bb * 128 + h)) * CIN + cc];
        xs[idx] = s;
    }
    __syncthreads();

    const int b    = tid >> 6;
    const int lane = tid & 63;                  // mid
    const float4* wr = (const float4*)(Wm + (size_t)lane * CIN);
    const float4* xr = (const float4*)(&xs[b * CIN]);
    float dot = 0.f;
    #pragma unroll 8
    for (int c4 = 0; c4 < CIN / 4; ++c4) {
        const float4 w = wr[c4], xv = xr[c4];   // xv: wave-uniform broadcast
        dot += w.x * xv.x + w.y * xv.y + w.z * xv.z + w.w * xv.w;
    }
    const float sv = 1.0f / (1.0f + __expf(-(dot * (1.0f / 16384.0f) + bvec[lane])));
    float val      = sv;
    float selected = 0.0f;
    for (int t = 0; t < k; ++t) {
        float bvv = val;
        int   bi  = lane;
        #pragma unroll
        for (int off = 32; off >= 1; off >>= 1) {
            const float ov = __shfl_xor(bvv, off);
            const int   oi = __shfl_xor(bi, off);
            if (ov > bvv || (ov == bvv && oi < bi)) { bvv = ov; bi = oi; }
        }
        if (lane == bi) { val = -INFINITY; selected = 1.0f; }
        if (lane == 0) out[IDX_OFF + b * k + t] = (float)bi;
    }
    out[b * NMID + lane] = selected;            // mask
    if (tid == 0) out[K_OFF] = (float)k;
}

// ---------------------------------------------------------------------------
extern "C" void kernel_launch(void* const* d_in, const int* in_sizes, int n_in,
                              void* d_out, int out_size, void* d_ws, size_t ws_size,
                              hipStream_t stream)
{
    const float* x    = (const float*)d_in[0];
    const float* Wm   = (const float*)d_in[1];
    const float* bvec = (const float*)d_in[2];
    float* out   = (float*)d_out;
    char*  ws    = (char*)d_ws;             // 1 MB W image + 1 MB xpart
    float* xpart = (float*)(ws + XPART_OFF);

    // out_size = 512 (mask) + 75497472 (norm_kernels) + 1 (k) + 8*k (indices)
    const int k = (out_size - IDX_OFF) / 8;

    prep_w<<<640, 256, 0, stream>>>(Wm, ws);
    fused_main<<<8 * (HW / HWTILE), 256, 0, stream>>>(x, ws, bvec, out, xpart);
    finalize_kernel<<<1, 512, 0, stream>>>(out, Wm, bvec, xpart, k);
}